// Round 2
// 203.735 us; speedup vs baseline: 1.0728x; 1.0728x over previous
//
#include <hip/hip_runtime.h>
#include <hip/hip_bf16.h>

#define Hh 512
#define Pp 256
#define Ll 4096
#define Bb 8
#define BL (Bb*Ll)      // 32768
#define Sc 64
#define NC 64

typedef __attribute__((ext_vector_type(8))) __bf16 bf16x8;
typedef __attribute__((ext_vector_type(4))) float  floatx4;

// ws offsets in float2 units (8 B each; all 16B-aligned)
#define LAM_OFF     0                        // f32 lambda_bar [256]
#define LAMS64D_OFF 512                      // double2 lambda^64 [256] (512 slots)
#define B1G_OFF     1024                     // bf16 [512 n][512 k]
#define B3G_OFF     (B1G_OFF + 65536)        // bf16 [512 n][512 k]
#define UB16_OFF    (B3G_OFF + 65536)        // bf16 u [32768][512]
#define BUB_OFF     (UB16_OFF + 4194304)     // bf16 Bu [32768][512]
#define XSB_OFF     (BUB_OFF + 4194304)      // bf16 xs [32768][512]
#define AGG_OFF     (XSB_OFF + 4194304)      // float2 [512*256]

#define OUT_ELEMS 16777216                   // then state planar [2048 re][2048 im]

#define GLL16(g, l) __builtin_amdgcn_global_load_lds( \
    (const __attribute__((address_space(1))) void*)(g), \
    (__attribute__((address_space(3))) void*)(l), 16, 0, 0)

// raw barrier + counted waits (no __syncthreads: its vmcnt(0) drain kills the pipeline)
#define BAR_LGKM()  asm volatile("s_waitcnt lgkmcnt(0)\n\ts_barrier" ::: "memory")
#define BAR_VMN(n)  asm volatile("s_waitcnt vmcnt(" #n ")\n\ts_barrier" ::: "memory")

__device__ __forceinline__ float2 cmul(float2 a, float2 b) {
    return make_float2(a.x*b.x - a.y*b.y, a.x*b.y + a.y*b.x);
}
__device__ __forceinline__ void cfma(float2& acc, float2 a, float2 b) {
    acc.x = fmaf(a.x, b.x, acc.x); acc.x = fmaf(-a.y, b.y, acc.x);
    acc.y = fmaf(a.x, b.y, acc.y); acc.y = fmaf( a.y, b.x, acc.y);
}

// ---- PREP: grid 9217. (unchanged)
__global__ void prep(const float* __restrict__ u,
                     const float* __restrict__ Bmat, const float* __restrict__ Cmat,
                     const float* __restrict__ Lre, const float* __restrict__ Lim,
                     const float* __restrict__ logstep, float2* __restrict__ ws) {
    int bid = blockIdx.x;
    if (bid < 8192) {
        long i = ((long)bid * 256 + threadIdx.x) * 8;
        float4 v0 = *(const float4*)(u + i);
        float4 v1 = *(const float4*)(u + i + 4);
        __align__(16) __hip_bfloat162 t[4];
        t[0] = __float22bfloat162_rn(make_float2(v0.x, v0.y));
        t[1] = __float22bfloat162_rn(make_float2(v0.z, v0.w));
        t[2] = __float22bfloat162_rn(make_float2(v1.x, v1.y));
        t[3] = __float22bfloat162_rn(make_float2(v1.z, v1.w));
        *(bf16x8*)((__hip_bfloat16*)(ws + UB16_OFF) + i) = *(const bf16x8*)t;
    } else if (bid < 8704) {
        int idx = (bid - 8192) * 256 + threadIdx.x;  // = p*512+h
        int p = idx >> 9, h = idx & 511;
        double lr = (double)Lre[p], li = (double)Lim[p];
        double st = exp((double)logstep[p]);
        double a  = lr * st, th = li * st;
        double er = exp(a);
        double lamr = er * cos(th), lami = er * sin(th);
        double nr = lamr - 1.0, ni = lami;
        double den = lr*lr + li*li;
        float gx = (float)((nr*lr + ni*li)/den), gy = (float)((ni*lr - nr*li)/den);
        float2 b = ((const float2*)Bmat)[idx];
        float re = gx*b.x - gy*b.y;
        float im = gx*b.y + gy*b.x;
        __hip_bfloat16* B1 = (__hip_bfloat16*)(ws + B1G_OFF);
        B1[(2*p)*512 + h]   = __float2bfloat16(re);
        B1[(2*p+1)*512 + h] = __float2bfloat16(im);
    } else if (bid < 9216) {
        int idx = (bid - 8704) * 256 + threadIdx.x;  // = h*256+p
        int h = idx >> 8, p = idx & 255;
        float2 c = ((const float2*)Cmat)[idx];
        __hip_bfloat162* B3 = (__hip_bfloat162*)(ws + B3G_OFF);
        B3[h*256 + p] = __float22bfloat162_rn(make_float2(2.f*c.x, -2.f*c.y));
    } else {
        int p = threadIdx.x;
        double lr = (double)Lre[p], li = (double)Lim[p];
        double st = exp((double)logstep[p]);
        double a  = lr * st, th = li * st;
        double er = exp(a);
        ws[LAM_OFF + p] = make_float2((float)(er*cos(th)), (float)(er*sin(th)));
        double er64 = exp(64.0 * a), th64 = 64.0 * th;
        ((double2*)(ws + LAMS64D_OFF))[p] = make_double2(er64*cos(th64), er64*sin(th64));
    }
}

// ---- 8-wave deep-pipelined 256x256 GEMM, BK=64 (T1+T2+T3/T4+T5) ----
// A [32768][512] bf16 row-major, B [512][512] bf16 row-major (K contiguous).
// EPI=0: Cout bf16 = acc. EPI=1: Cout fp32 = acc + Dv[col]*u_bf16.
// Grid 256 blocks x 512 threads (1 block/CU, 2 waves/SIMD).
// LDS: 2 buf x (A 32K + B 32K) = 128 KB.
// T2 swizzle both-sides (rule 21): LDS[row][slot] holds global slot (slot^(row&7));
// achieved by inverse-swizzling the per-lane GLOBAL source (linear LDS dest for
// global_load_lds), undone on the ds_read side via o0/o1.
// Per K-tile: 2 phases (ks=0/1), 12 frag reads + 32 MFMA each -> peak live regs
// ~200 (acc 128 + frags 48 + addr), fits 256-VGPR @ 2 waves/SIMD without spill.
#define STAGE(buf, kt) do { \
    _Pragma("unroll") \
    for (int h_ = 0; h_ < 2; ++h_) { \
        _Pragma("unroll") \
        for (int r_ = 0; r_ < 2; ++r_) { \
            GLL16(aSrc + (h_*128 + r_*64)*1024 + (kt)*128, \
                  ldsSt + (buf)*65536 + h_*16384 + r_*8192); \
            GLL16(bSrc + (h_*128 + r_*64)*1024 + (kt)*128, \
                  ldsSt + (buf)*65536 + 32768 + h_*16384 + r_*8192); \
        } \
    } \
} while (0)

template<int EPI>
__global__ __launch_bounds__(512, 2)
void gemm8(const __hip_bfloat16* __restrict__ A,
           const __hip_bfloat16* __restrict__ B,
           void* __restrict__ Cout,
           const __hip_bfloat16* __restrict__ ub,
           const float* __restrict__ Dv) {
    __shared__ __align__(16) char lds[131072];
    const int tid = threadIdx.x;
    const int w = tid >> 6, l = tid & 63;

    // T1: bijective XCD swizzle (256 % 8 == 0): each XCD gets 32 consecutive
    // tile indices -> contiguous M-range per XCD, B-panel reuse in its L2.
    const int idx = blockIdx.x;
    const int swz = (idx & 7) * 32 + (idx >> 3);
    const int mt = swz >> 1, nt = swz & 1;
    const long M0 = (long)mt * 256;
    const int  N0 = nt * 256;

    // staging: lane l writes LDS slot (l&7) of row (w*8 + (l>>3)) [linear dest];
    // global source col-slot = (l&7) ^ (l>>3), so LDS[row][s] = global slot s^(row&7).
    const int rA  = l >> 3;
    const int csw = ((l & 7) ^ rA) * 16;
    const char* aSrc = (const char*)A + (M0 + w*8 + rA) * 1024 + csw;
    const char* bSrc = (const char*)B + (long)(N0 + w*8 + rA) * 1024 + csw;
    char* ldsSt = lds + w*1024 + l*16;

    // fragment-read bases: A rows linear at row*128B within buf; slot read = q^(row&7)
    const int quad = l >> 4, ml = l & 15, m7 = ml & 7;
    const int wm = w & 1, wn = w >> 1;
    const int o0 = ((quad    ) ^ m7) * 16;   // ks=0: global slot quad
    const int o1 = ((quad + 4) ^ m7) * 16;   // ks=1: global slot quad+4
    const char* aRd = lds + wm*16384 + ml*128;
    const char* bRd = lds + 32768 + (wn >> 1)*16384 + ((wn & 1)*64 + ml)*128;

    floatx4 acc[8][4];
    #pragma unroll
    for (int i = 0; i < 8; ++i)
        #pragma unroll
        for (int j = 0; j < 4; ++j) acc[i][j] = (floatx4)0.f;

    // prologue: stage K-tiles 0,1; wait tile-0 (8 newest = tile-1 still in flight)
    STAGE(0, 0);
    STAGE(1, 1);
    BAR_VMN(8);

    #pragma unroll
    for (int t = 0; t < 8; ++t) {
        const int tb = (t & 1) * 65536;

        // ---- phase ks=0: 12 frag reads + 32 MFMA (compiler auto-waits lgkm) ----
        {
            bf16x8 af[8], bfr[4];
            #pragma unroll
            for (int fm = 0; fm < 8; ++fm)
                af[fm] = *(const bf16x8*)(aRd + tb + fm*2048 + o0);
            #pragma unroll
            for (int fn = 0; fn < 4; ++fn)
                bfr[fn] = *(const bf16x8*)(bRd + tb + fn*2048 + o0);
            __builtin_amdgcn_s_setprio(1);
            #pragma unroll
            for (int fm = 0; fm < 8; ++fm)
                #pragma unroll
                for (int fn = 0; fn < 4; ++fn)
                    acc[fm][fn] = __builtin_amdgcn_mfma_f32_16x16x32_bf16(
                        af[fm], bfr[fn], acc[fm][fn], 0, 0, 0);
            __builtin_amdgcn_s_setprio(0);
        }

        // ---- phase ks=1: 12 frag reads, then buf is free -> prefetch t+2 ----
        {
            bf16x8 af[8], bfr[4];
            #pragma unroll
            for (int fm = 0; fm < 8; ++fm)
                af[fm] = *(const bf16x8*)(aRd + tb + fm*2048 + o1);
            #pragma unroll
            for (int fn = 0; fn < 4; ++fn)
                bfr[fn] = *(const bf16x8*)(bRd + tb + fn*2048 + o1);
            // all waves done reading buf (lgkmcnt(0) drains own ds_reads; barrier
            // syncs waves) -> safe to overwrite buf with tile t+2
            BAR_LGKM();
            if (t + 2 < 8) STAGE(t & 1, t + 2);
            __builtin_amdgcn_sched_barrier(0);
            __builtin_amdgcn_s_setprio(1);
            #pragma unroll
            for (int fm = 0; fm < 8; ++fm)
                #pragma unroll
                for (int fn = 0; fn < 4; ++fn)
                    acc[fm][fn] = __builtin_amdgcn_mfma_f32_16x16x32_bf16(
                        af[fm], bfr[fn], acc[fm][fn], 0, 0, 0);
            __builtin_amdgcn_s_setprio(0);
        }

        // counted wait: tile t+1 landed (<=8 newest outstanding = tile t+2's).
        // t==6: no stage was issued this iter -> drain to 0 for tile 7.
        if (t < 6)       BAR_VMN(8);
        else if (t == 6) BAR_VMN(0);
        // t==7: fall through to epilogue
    }

    #pragma unroll
    for (int fm = 0; fm < 8; ++fm)
        #pragma unroll
        for (int fn = 0; fn < 4; ++fn) {
            const int col = N0 + wn*64 + fn*16 + ml;
            const float d = (EPI == 1) ? Dv[col] : 0.f;
            #pragma unroll
            for (int reg = 0; reg < 4; ++reg) {
                const long row = M0 + wm*128 + fm*16 + quad*4 + reg;
                const long o = row * 512 + col;
                if (EPI == 0) {
                    ((__hip_bfloat16*)Cout)[o] = __float2bfloat16(acc[fm][fn][reg]);
                } else {
                    ((float*)Cout)[o] = acc[fm][fn][reg] + d * __bfloat162float(ub[o]);
                }
            }
        }
}

// ---- K2a: chunk aggregates, lambda-power ILP grouping (unchanged) ----
__global__ void k2a(float2* __restrict__ ws) {
    int p = threadIdx.x;
    int bc = blockIdx.x;              // b*NC + c
    int b = bc >> 6, c = bc & 63;
    float2 lam = ws[LAM_OFF + p];
    float2 lp[8];
    lp[0] = make_float2(1.f, 0.f);
    #pragma unroll
    for (int k = 1; k < 8; ++k) lp[k] = cmul(lp[k-1], lam);
    float2 lam8 = cmul(lp[7], lam);
    const __hip_bfloat162* __restrict__ bub = (const __hip_bfloat162*)(ws + BUB_OFF);
    long base = (long)(b*Ll + c*Sc) * Pp + p;
    float2 agg = make_float2(0.f, 0.f);
    for (int j0 = 0; j0 < Sc; j0 += 8) {
        float2 v[8];
        #pragma unroll
        for (int i = 0; i < 8; ++i)
            v[i] = __bfloat1622float2(bub[base + (long)(j0 + i) * Pp]);
        float2 s0 = make_float2(0.f, 0.f), s1 = make_float2(0.f, 0.f);
        #pragma unroll
        for (int i = 0; i < 8; i += 2) {
            cfma(s0, lp[7 - i], v[i]);
            cfma(s1, lp[6 - i], v[i + 1]);
        }
        float2 G = make_float2(s0.x + s1.x, s0.y + s1.y);
        float2 na = cmul(lam8, agg);
        agg = make_float2(na.x + G.x, na.y + G.y);
    }
    ws[AGG_OFF + bc * Pp + p] = agg;
}

// ---- K2c: fp64 carry prefix + apply + write xs bf16 + state planar (unchanged) ----
__global__ void k2c(float2* __restrict__ ws, float* __restrict__ dout) {
    int p = threadIdx.x;
    int bc = blockIdx.x;
    int b = bc >> 6, c = bc & 63;
    float2 lam = ws[LAM_OFF + p];
    double2 l64 = ((const double2*)(ws + LAMS64D_OFF))[p];
    double cr = 0.0, ci = 0.0;
    for (int cp = 0; cp < c; ++cp) {
        float2 a = ws[AGG_OFF + (b*NC + cp) * Pp + p];
        double nr = fma(l64.x, cr, (double)a.x); nr = fma(-l64.y, ci, nr);
        double ni = fma(l64.x, ci, (double)a.y); ni = fma( l64.y, cr, ni);
        cr = nr; ci = ni;
    }
    float2 x = make_float2((float)cr, (float)ci);
    const __hip_bfloat162* __restrict__ bub = (const __hip_bfloat162*)(ws + BUB_OFF);
    __hip_bfloat162* __restrict__ xsb = (__hip_bfloat162*)(ws + XSB_OFF);
    long base = (long)(b*Ll + c*Sc) * Pp + p;
    for (int j0 = 0; j0 < Sc; j0 += 8) {
        float2 v[8];
        #pragma unroll
        for (int i = 0; i < 8; ++i)
            v[i] = __bfloat1622float2(bub[base + (long)(j0 + i) * Pp]);
        #pragma unroll
        for (int i = 0; i < 8; ++i) {
            float nr = fmaf(lam.x, x.x, v[i].x); nr = fmaf(-lam.y, x.y, nr);
            float ni = fmaf(lam.x, x.y, v[i].y); ni = fmaf( lam.y, x.x, ni);
            x.x = nr; x.y = ni;
            xsb[base + (long)(j0 + i) * Pp] = __float22bfloat162_rn(make_float2(x.x, x.y));
        }
    }
    if (c == NC - 1) {
        dout[OUT_ELEMS + b * Pp + p] = x.x;
        dout[OUT_ELEMS + Bb * Pp + b * Pp + p] = x.y;
    }
}

extern "C" void kernel_launch(void* const* d_in, const int* in_sizes, int n_in,
                              void* d_out, int out_size, void* d_ws, size_t ws_size,
                              hipStream_t stream) {
    const float* u       = (const float*)d_in[0];
    const float* Lre     = (const float*)d_in[1];
    const float* Lim     = (const float*)d_in[2];
    const float* Bmat    = (const float*)d_in[3];
    const float* Cmat    = (const float*)d_in[4];
    const float* Dv      = (const float*)d_in[5];
    const float* logstep = (const float*)d_in[6];
    float*  out = (float*)d_out;
    float2* ws  = (float2*)d_ws;

    prep<<<9217, 256, 0, stream>>>(u, Bmat, Cmat, Lre, Lim, logstep, ws);

    gemm8<0><<<256, 512, 0, stream>>>(
        (const __hip_bfloat16*)(ws + UB16_OFF),
        (const __hip_bfloat16*)(ws + B1G_OFF),
        (void*)(ws + BUB_OFF), nullptr, nullptr);

    k2a<<<Bb*NC, 256, 0, stream>>>(ws);
    k2c<<<Bb*NC, 256, 0, stream>>>(ws, out);

    gemm8<1><<<256, 512, 0, stream>>>(
        (const __hip_bfloat16*)(ws + XSB_OFF),
        (const __hip_bfloat16*)(ws + B3G_OFF),
        (void*)out,
        (const __hip_bfloat16*)(ws + UB16_OFF), Dv);
}